// Round 1
// baseline (53.366 us; speedup 1.0000x reference)
//
#include <hip/hip_runtime.h>
#include <math.h>

// Shapes (hard-coded per reference setup_inputs):
//   b=16, t=128, c=t-1=127, kv_dim=k=64, h=4, q_dim=256
#define Bdim 16
#define Tdim 128
#define Cdim 127
#define Kdim 64
#define Hdim 4
#define QD   256
#define HK   256   // h*k

// Kernel A: M[i, h*64+j] = sum_k Wq[i, h*64+k] * Wk[j, h*64+k]
// (collapses the q-projection and K-projection into one 256x256 matrix)
__global__ __launch_bounds__(256) void precompute_M(
        const float* __restrict__ Wq,
        const float* __restrict__ Wk,
        float* __restrict__ M) {
    int i   = blockIdx.x;       // 0..255 (q_dim)
    int tid = threadIdx.x;      // 0..255 = h*64 + j
    int h = tid >> 6, j = tid & 63;
    const float* wq = Wq + i * HK + h * 64;
    const float* wk = Wk + j * HK + h * 64;
    float s = 0.f;
    #pragma unroll
    for (int k = 0; k < 64; ++k) s += wq[k] * wk[k];
    M[i * HK + tid] = s;
}

// Kernel B: qk[bt, :] = q_x[bt, :] @ M   ([2048,256] @ [256,256])
// 256 blocks x 256 threads; each block computes 8 rows, thread = one column.
__global__ __launch_bounds__(256) void qk_gemm(
        const float* __restrict__ q_x,
        const float* __restrict__ M,
        float* __restrict__ qk) {
    __shared__ float qls[8 * QD];
    int blk = blockIdx.x;
    int tid = threadIdx.x;
    const float* src = q_x + (size_t)blk * 8 * QD;
    for (int idx = tid; idx < 8 * QD; idx += 256) qls[idx] = src[idx];
    __syncthreads();
    float acc[8] = {0.f,0.f,0.f,0.f,0.f,0.f,0.f,0.f};
    for (int i = 0; i < QD; ++i) {
        float m = M[i * HK + tid];          // coalesced row read
        #pragma unroll
        for (int r = 0; r < 8; ++r) acc[r] += qls[r * QD + i] * m;  // LDS broadcast
    }
    float* dst = qk + (size_t)blk * 8 * HK;
    #pragma unroll
    for (int r = 0; r < 8; ++r) dst[r * HK + tid] = acc[r];
}

// Kernel C: per (b,t) block — scores, softmax, context-contraction, V-proj.
//   scores[h,c] = (XT[:,c] . qk[h,:]) / 8
//   w = softmax_c(scores)
//   wx[h,j]     = sum_c w[h,c] * X[c,j]
//   out[h,k]    = sum_j wx[h,j] * Wv[j, h*64+k]
__global__ __launch_bounds__(256) void attn_main(
        const float* __restrict__ kv_x,
        const float* __restrict__ qk_all,
        const float* __restrict__ Wv,
        float* __restrict__ out) {
    // XT padded to 129 floats/row: addr = j*129 + c -> bank (j+c)%32 -> 2-way only
    __shared__ float sXT[64 * 129];
    __shared__ float qk_s[HK];
    __shared__ float w_lds[Hdim * 128];
    __shared__ float wx_lds[Hdim * 64];

    int bt  = blockIdx.x;
    int tid = threadIdx.x;

    // Stage kv_x[b,t] (127x64) transposed into LDS, float4 global loads.
    const float4* Xg = (const float4*)(kv_x + (size_t)bt * Cdim * Kdim);
    for (int v = tid; v < (Cdim * Kdim) / 4; v += 256) {
        float4 d = Xg[v];
        int base = v * 4;            // element idx = c*64 + j
        int c = base >> 6, j = base & 63;   // j in {0,4,...,60}: never crosses row
        sXT[(j + 0) * 129 + c] = d.x;
        sXT[(j + 1) * 129 + c] = d.y;
        sXT[(j + 2) * 129 + c] = d.z;
        sXT[(j + 3) * 129 + c] = d.w;
    }
    qk_s[tid] = qk_all[(size_t)bt * HK + tid];
    __syncthreads();

    int h = tid >> 6;        // wave -> head
    int lane = tid & 63;

    // scores: lane handles c = lane and c = lane+64
    float s0 = 0.f, s1 = 0.f;
    int c0 = lane, c1 = lane + 64;
    for (int j = 0; j < 64; ++j) {
        float qv = qk_s[h * 64 + j];        // LDS broadcast
        s0 += sXT[j * 129 + c0] * qv;       // 2-way bank alias (free)
        s1 += sXT[j * 129 + c1] * qv;       // c1==127 reads pad garbage; masked below
    }
    s0 *= 0.125f;                            // 1/sqrt(64)
    s1 = (c1 < Cdim) ? s1 * 0.125f : -INFINITY;

    // wave-wide softmax over 127 values (2 per lane)
    float m = fmaxf(s0, s1);
    #pragma unroll
    for (int mask = 32; mask >= 1; mask >>= 1)
        m = fmaxf(m, __shfl_xor(m, mask, 64));
    float e0 = expf(s0 - m);
    float e1 = (c1 < Cdim) ? expf(s1 - m) : 0.f;
    float sum = e0 + e1;
    #pragma unroll
    for (int mask = 32; mask >= 1; mask >>= 1)
        sum += __shfl_xor(sum, mask, 64);
    float inv = 1.f / sum;
    w_lds[h * 128 + c0] = e0 * inv;
    if (c1 < Cdim) w_lds[h * 128 + c1] = e1 * inv;
    __syncthreads();

    // wx[h][j]: lane = j
    float wx = 0.f;
    const float* wrow = &w_lds[h * 128];
    const float* xrow = &sXT[lane * 129];    // bank (lane+c)%32 -> 2-way (free)
    for (int c = 0; c < Cdim; ++c) wx += wrow[c] * xrow[c];
    wx_lds[h * 64 + lane] = wx;
    __syncthreads();

    // out projection: lane = k; Wv row reads coalesced (L2-hot, 64 KB matrix)
    float acc = 0.f;
    for (int j = 0; j < 64; ++j)
        acc += wx_lds[h * 64 + j] * Wv[j * HK + h * 64 + lane];
    out[(size_t)bt * HK + h * 64 + lane] = acc;
}

extern "C" void kernel_launch(void* const* d_in, const int* in_sizes, int n_in,
                              void* d_out, int out_size, void* d_ws, size_t ws_size,
                              hipStream_t stream) {
    const float* q_x  = (const float*)d_in[0];   // [16,128,256]
    const float* kv_x = (const float*)d_in[1];   // [16,128,127,64]
    const float* Wq   = (const float*)d_in[2];   // [256,256]
    const float* Wk   = (const float*)d_in[3];   // [64,256]
    const float* Wv   = (const float*)d_in[4];   // [64,256]
    float* out = (float*)d_out;                  // [16,128,256] f32

    float* M  = (float*)d_ws;                    // 256*256 floats
    float* qk = M + 256 * 256;                   // 2048*256 floats

    precompute_M<<<256, 256, 0, stream>>>(Wq, Wk, M);
    qk_gemm<<<256, 256, 0, stream>>>(q_x, M, qk);
    attn_main<<<Bdim * Tdim, 256, 0, stream>>>(kv_x, qk, Wv, out);
}